// Round 1
// baseline (2659.133 us; speedup 1.0000x reference)
//
#include <hip/hip_runtime.h>
#include <hip/hip_bf16.h>
#include <cstdint>

#define B_  2
#define CK_ 64
#define NM_ 32768
#define NQ_ 4096
#define CV_ 256
#define K_  20

// ---------------------------------------------------------------- a[b][m] = sum_c mk^2
__global__ __launch_bounds__(256) void sqnorm_kernel(const float* __restrict__ mk,
                                                     float* __restrict__ an) {
  int i = blockIdx.x * 256 + threadIdx.x;          // 0 .. B*NM
  int b = i >> 15, m = i & (NM_ - 1);
  const float* p = mk + (size_t)b * CK_ * NM_ + m;
  float s = 0.f;
  #pragma unroll
  for (int c = 0; c < CK_; ++c) { float v = p[(size_t)c * NM_]; s = fmaf(v, v, s); }
  an[i] = s;
}

// ---------------------------------------------------------------- mv[b][c][m] -> mvt[b][m][c]
__global__ __launch_bounds__(256) void transpose_kernel(const float* __restrict__ mv0,
                                                        const float* __restrict__ mv1,
                                                        float* __restrict__ mvt0,
                                                        float* __restrict__ mvt1) {
  __shared__ float tl[32][33];
  const int bank = blockIdx.z & 1, b = blockIdx.z >> 1;
  const float* src = (bank ? mv1 : mv0) + (size_t)b * CV_ * NM_;
  float*       dst = (bank ? mvt1 : mvt0) + (size_t)b * NM_ * CV_;
  const int m0 = blockIdx.x * 32, c0 = blockIdx.y * 32;
  const int tx = threadIdx.x, ty = threadIdx.y;    // 32 x 8
  #pragma unroll
  for (int i = 0; i < 4; ++i)
    tl[ty + 8 * i][tx] = src[(size_t)(c0 + ty + 8 * i) * NM_ + m0 + tx];
  __syncthreads();
  #pragma unroll
  for (int i = 0; i < 4; ++i)
    dst[(size_t)(m0 + ty + 8 * i) * CV_ + c0 + tx] = tl[tx][ty + 8 * i];
}

// ---------------------------------------------------------------- scores + running top-20
// block: 256 threads, 1 query/thread. grid: (NQ/256, S, B). Each block scans MSEG m-entries.
__global__ __launch_bounds__(256) void score_topk_kernel(const float* __restrict__ mk,
                                                         const float* __restrict__ qk,
                                                         const float* __restrict__ an,
                                                         float* __restrict__ pvals,
                                                         int* __restrict__ pidx,
                                                         int S, int MSEG) {
  __shared__ float tile[CK_][64];   // [c][mp]  (mp contiguous)
  __shared__ float atile[64];
  const int t = threadIdx.x;
  const int b = blockIdx.z, seg = blockIdx.y;
  const int q = blockIdx.x * 256 + t;

  float qreg[CK_];
  #pragma unroll
  for (int c = 0; c < CK_; ++c) qreg[c] = qk[(size_t)(b * CK_ + c) * NQ_ + q];

  float vals[K_]; int idxs[K_];
  #pragma unroll
  for (int j = 0; j < K_; ++j) { vals[j] = -3.4e38f; idxs[j] = 0; }

  auto ins = [&](float s, int m) {
    if (s > vals[K_ - 1]) {
      vals[K_ - 1] = s; idxs[K_ - 1] = m;
      #pragma unroll
      for (int j = K_ - 1; j > 0; --j) {
        if (vals[j] > vals[j - 1]) {
          float tv = vals[j]; vals[j] = vals[j - 1]; vals[j - 1] = tv;
          int   ti = idxs[j]; idxs[j] = idxs[j - 1]; idxs[j - 1] = ti;
        }
      }
    }
  };

  const int m0seg = seg * MSEG;
  for (int mc = 0; mc < MSEG; mc += 64) {
    const int m0 = m0seg + mc;
    // stage mk[b][0:64][m0:m0+64] into LDS (coalesced, conflict-free)
    #pragma unroll
    for (int r = 0; r < 4; ++r) {
      int f = t + 256 * r;                 // float4 index 0..1023
      int c = f >> 4, m4 = f & 15;
      float4 v = *reinterpret_cast<const float4*>(mk + (size_t)(b * CK_ + c) * NM_ + m0 + 4 * m4);
      *reinterpret_cast<float4*>(&tile[c][4 * m4]) = v;
    }
    if (t < 16) {
      float4 v = *reinterpret_cast<const float4*>(an + (size_t)b * NM_ + m0 + 4 * t);
      *reinterpret_cast<float4*>(&atile[4 * t]) = v;
    }
    __syncthreads();

    for (int g = 0; g < 16; ++g) {         // 4 m-entries per group
      float s0 = 0.f, s1 = 0.f, s2 = 0.f, s3 = 0.f;
      #pragma unroll
      for (int c = 0; c < CK_; ++c) {
        float4 mv = *reinterpret_cast<const float4*>(&tile[c][4 * g]);  // wave-uniform broadcast
        float qv = qreg[c];
        s0 = fmaf(mv.x, qv, s0);
        s1 = fmaf(mv.y, qv, s1);
        s2 = fmaf(mv.z, qv, s2);
        s3 = fmaf(mv.w, qv, s3);
      }
      float4 av = *reinterpret_cast<const float4*>(&atile[4 * g]);
      s0 = (2.f * s0 - av.x) * 0.125f;
      s1 = (2.f * s1 - av.y) * 0.125f;
      s2 = (2.f * s2 - av.z) * 0.125f;
      s3 = (2.f * s3 - av.w) * 0.125f;
      int mb = m0 + 4 * g;
      ins(s0, mb + 0); ins(s1, mb + 1); ins(s2, mb + 2); ins(s3, mb + 3);
    }
    __syncthreads();
  }

  #pragma unroll
  for (int j = 0; j < K_; ++j) {
    size_t o = (size_t)((b * S + seg) * K_ + j) * NQ_ + q;
    pvals[o] = vals[j]; pidx[o] = idxs[j];
  }
}

// ---------------------------------------------------------------- merge segments + softmax
__global__ __launch_bounds__(256) void merge_kernel(const float* __restrict__ pvals,
                                                    const int* __restrict__ pidx,
                                                    float* __restrict__ fw,
                                                    int* __restrict__ fidx, int S) {
  int i = blockIdx.x * 256 + threadIdx.x;          // 0 .. B*NQ
  int b = i >> 12, q = i & (NQ_ - 1);

  float vals[K_]; int idxs[K_];
  #pragma unroll
  for (int j = 0; j < K_; ++j) { vals[j] = -3.4e38f; idxs[j] = 0; }

  for (int seg = 0; seg < S; ++seg) {
    #pragma unroll
    for (int j = 0; j < K_; ++j) {
      size_t o = (size_t)((b * S + seg) * K_ + j) * NQ_ + q;
      float v = pvals[o];
      if (v > vals[K_ - 1]) {
        int m = pidx[o];
        vals[K_ - 1] = v; idxs[K_ - 1] = m;
        #pragma unroll
        for (int jj = K_ - 1; jj > 0; --jj) {
          if (vals[jj] > vals[jj - 1]) {
            float tv = vals[jj]; vals[jj] = vals[jj - 1]; vals[jj - 1] = tv;
            int   ti = idxs[jj]; idxs[jj] = idxs[jj - 1]; idxs[jj - 1] = ti;
          }
        }
      }
    }
  }

  float mx = vals[0];
  float w[K_]; float sum = 0.f;
  #pragma unroll
  for (int j = 0; j < K_; ++j) { w[j] = expf(vals[j] - mx); sum += w[j]; }
  float inv = 1.f / sum;
  #pragma unroll
  for (int j = 0; j < K_; ++j) {
    size_t o = (size_t)(b * K_ + j) * NQ_ + q;
    fw[o] = w[j] * inv; fidx[o] = idxs[j];
  }
}

// ---------------------------------------------------------------- sparse readout
// block: 256 threads (thread==channel), 16 queries/block. grid: (NQ/16, B)
template <bool TP>
__global__ __launch_bounds__(256) void readout_kernel(const float* __restrict__ v0src,
                                                      const float* __restrict__ v1src,
                                                      const float* __restrict__ fw,
                                                      const int* __restrict__ fidx,
                                                      float* __restrict__ out) {
  __shared__ float mw[16][K_];
  __shared__ int   mi[16][K_];
  __shared__ float ob0[256][17];
  __shared__ float ob1[256][17];
  const int t = threadIdx.x;
  const int b = blockIdx.y;
  const int q0 = blockIdx.x * 16;

  for (int i = t; i < 16 * K_; i += 256) {
    int qp = i / K_, k = i % K_;
    size_t o = (size_t)(b * K_ + k) * NQ_ + q0 + qp;
    mw[qp][k] = fw[o];
    mi[qp][k] = fidx[o];
  }
  __syncthreads();

  for (int qp = 0; qp < 16; ++qp) {
    float a0 = 0.f, a1 = 0.f;
    #pragma unroll 5
    for (int k = 0; k < K_; ++k) {
      int m = mi[qp][k]; float ww = mw[qp][k];
      size_t o;
      if (TP) o = (size_t)(b * NM_ + m) * CV_ + t;
      else    o = (size_t)b * CV_ * NM_ + (size_t)t * NM_ + m;
      a0 = fmaf(ww, v0src[o], a0);
      a1 = fmaf(ww, v1src[o], a1);
    }
    ob0[t][qp] = a0; ob1[t][qp] = a1;
  }
  __syncthreads();

  float* out0 = out + (size_t)b * CV_ * NQ_;
  float* out1 = out + (size_t)B_ * CV_ * NQ_ + (size_t)b * CV_ * NQ_;
  for (int i = t; i < 256 * 16; i += 256) {
    int c = i >> 4, qp = i & 15;
    out0[(size_t)c * NQ_ + q0 + qp] = ob0[c][qp];
    out1[(size_t)c * NQ_ + q0 + qp] = ob1[c][qp];
  }
}

// ----------------------------------------------------------------
extern "C" void kernel_launch(void* const* d_in, const int* in_sizes, int n_in,
                              void* d_out, int out_size, void* d_ws, size_t ws_size,
                              hipStream_t stream) {
  (void)in_sizes; (void)n_in; (void)out_size;
  const float* mk  = (const float*)d_in[0];
  const float* qk  = (const float*)d_in[1];
  const float* mv0 = (const float*)d_in[2];
  const float* mv1 = (const float*)d_in[3];
  float* out = (float*)d_out;

  auto al = [](size_t x) { return (x + 255) & ~(size_t)255; };
  const size_t aB   = (size_t)B_ * NM_ * sizeof(float);
  const size_t finB = (size_t)B_ * K_ * NQ_ * sizeof(float);
  const size_t tpB  = (size_t)B_ * NM_ * CV_ * sizeof(float);
  auto partB = [](int S) { return (size_t)B_ * S * K_ * NQ_ * sizeof(float); };

  int S; bool tp;
  if      (ws_size >= al(aB) + 2 * al(partB(16)) + 2 * al(finB) + 2 * al(tpB)) { S = 16; tp = true;  }
  else if (ws_size >= al(aB) + 2 * al(partB(16)) + 2 * al(finB))               { S = 16; tp = false; }
  else if (ws_size >= al(aB) + 2 * al(partB(4))  + 2 * al(finB))               { S = 4;  tp = false; }
  else                                                                         { S = 1;  tp = false; }

  char* p = (char*)d_ws;
  float* an    = (float*)p; p += al(aB);
  float* pvals = (float*)p; p += al(partB(S));
  int*   pidx  = (int*)p;   p += al(partB(S));
  float* fw    = (float*)p; p += al(finB);
  int*   fidx  = (int*)p;   p += al(finB);
  float* mvt0 = nullptr, * mvt1 = nullptr;
  if (tp) { mvt0 = (float*)p; p += al(tpB); mvt1 = (float*)p; p += al(tpB); }

  sqnorm_kernel<<<B_ * NM_ / 256, 256, 0, stream>>>(mk, an);
  if (tp)
    transpose_kernel<<<dim3(NM_ / 32, CV_ / 32, B_ * 2), dim3(32, 8), 0, stream>>>(mv0, mv1, mvt0, mvt1);
  score_topk_kernel<<<dim3(NQ_ / 256, S, B_), 256, 0, stream>>>(mk, qk, an, pvals, pidx, S, NM_ / S);
  merge_kernel<<<B_ * NQ_ / 256, 256, 0, stream>>>(pvals, pidx, fw, fidx, S);
  if (tp) readout_kernel<true ><<<dim3(NQ_ / 16, B_), 256, 0, stream>>>(mvt0, mvt1, fw, fidx, out);
  else    readout_kernel<false><<<dim3(NQ_ / 16, B_), 256, 0, stream>>>(mv0, mv1, fw, fidx, out);
}